// Round 27
// baseline (32.198 us; speedup 1.0000x reference)
//
#include <hip/hip_runtime.h>
#include <cstdint>
#include <cstddef>

typedef __attribute__((ext_vector_type(8))) short bf16x8;
typedef __attribute__((ext_vector_type(8))) _Float16 f16x8;
typedef __attribute__((ext_vector_type(4))) float f32x4;
typedef __attribute__((ext_vector_type(2))) float f32x2;
typedef __attribute__((ext_vector_type(2))) unsigned int u32x2;

static constexpr int BROWS  = 262144;
static constexpr int DIM    = 64;
static constexpr int NC     = 256;
static constexpr int OUTD   = 18;
static constexpr int BM     = 32;              // rows per chunk
static constexpr int NCHTOT = BROWS / BM;      // 8192 chunks
static constexpr int NBLK   = 768;             // 3 blocks/CU x 256 CUs (49KB LDS each)

__device__ __forceinline__ unsigned cvt_pk_bf16(float a, float b) {
  unsigned r;
  asm("v_cvt_pk_bf16_f32 %0, %1, %2" : "=v"(r) : "v"(a), "v"(b));
  return r;
}

union U4 { unsigned u[4]; bf16x8 v; };

// pack 8 f32 -> 8 bf16 (RN), order-preserving
__device__ __forceinline__ bf16x8 pack8(const float* s) {
  U4 r;
#pragma unroll
  for (int p = 0; p < 4; ++p) r.u[p] = cvt_pk_bf16(s[2*p], s[2*p+1]);
  return r.v;
}

// Base: R20/R26 (best measured 31.3us). Change this round: 2-deep x prefetch
// (pA/pB named register sets; issue chunk k+2 at iter k, consume pA at S1c)
// so the vmcnt wait before the LDS write is covered by a full chunk (~1500cy)
// instead of P1 only (~450cy < HBM latency).
// NOTE (gfx950): __launch_bounds__(512, 8) forces 32-VGPR cap -> spill (R9).
// NOTE: prefetch->LDS pipeline is LOAD-BEARING (R24: removing it -> 100us).
// NOTE: epilogue-rewrite family {C-init=brf, SC-fold, v_fract, cvt_pkrtz}
// BANNED (0.15-class failures in R5/R7/R17, mechanism unknown).
__global__ __launch_bounds__(512, 4) void rbf_fused(
    const float* __restrict__ x,  const float* __restrict__ Wr,
    const float* __restrict__ br, const float* __restrict__ Wl,
    const float* __restrict__ bl, float* __restrict__ out)
{
  __shared__ __align__(16) unsigned short xh16[2][BM * DIM];    // x as fp16 bits, 2 x 4 KB
  __shared__ __align__(16) unsigned short featb[2][BM * NC];    // feat bf16 bits, 2 x 16 KB
  __shared__ __align__(16) unsigned short wlds[OUTD * NC];      // W_lin bf16 (raw), 9 KB

  const int tid  = threadIdx.x;
  const int wav  = tid >> 6;      // 0..7
  const int lane = tid & 63;
  const int li   = lane & 15;
  const int g    = lane >> 4;

  const float S1 = 0.22507907903927651f;  // sqrt(2)/(2*pi): proj in revolutions
  const float SC = 0.08838834764831845f;  // sqrt(2/256), applied to feat

  // ---- stage W_lin -> LDS (bf16, swizzled) ----
  for (int idx = tid; idx < OUTD * 32; idx += 512) {
    const int r = idx >> 5, c = idx & 31;
    f32x4 v0 = *(const f32x4*)(Wl + r*NC + 8*c);
    f32x4 v1 = *(const f32x4*)(Wl + r*NC + 8*c + 4);
    float v[8];
    v[0]=v0.x; v[1]=v0.y; v[2]=v0.z; v[3]=v0.w;
    v[4]=v1.x; v[5]=v1.y; v[6]=v1.z; v[7]=v1.w;
    *(bf16x8*)(&wlds[r*NC + 8*(c ^ (r & 7))]) = pack8(v);
  }

  // ---- hoist A1 = (S1 * W_rbf)^T tile fragments, single fp16.  nt = 2*wav + q ----
  f16x8 a1[2][2];
#pragma unroll
  for (int q = 0; q < 2; ++q) {
    const int n = 16 * (2*wav + q) + li;      // component index
#pragma unroll
    for (int kb = 0; kb < 2; ++kb) {
      f16x8 f;
#pragma unroll
      for (int j = 0; j < 8; ++j)
        f[j] = (_Float16)(Wr[(size_t)(32*kb + 8*g + j) * NC + n] * S1);
      a1[q][kb] = f;
    }
  }
  f32x4 brf[2];
#pragma unroll
  for (int q = 0; q < 2; ++q)
    brf[q] = *(const f32x4*)(br + 16*(2*wav + q) + 4*g);

  const f32x4 bl0 = *(const f32x4*)(bl + 4*g);   // o = 4g..4g+3 <= 15 < 18
  const float bl16 = bl[16], bl17 = bl[17];
  const int rowc = (li < 2) ? (16 + li) : li;    // o-tile-1 A2 row (dummy rows harmless)

  const int sr = tid >> 4;   // staging row 0..31
  const int g4 = tid & 15;   // staging 4-float granule 0..15

  // stage-write: f32x4 -> fp16 (RNE), 8B write, 16B-chunk XOR swizzle
  // (chunk c16 = (g4>>1)^(sr&7)).
  auto stage_write = [&](int p, f32x4 v) {
    union { _Float16 h[4]; u32x2 u; } cv;
    cv.h[0] = (_Float16)v.x; cv.h[1] = (_Float16)v.y;
    cv.h[2] = (_Float16)v.z; cv.h[3] = (_Float16)v.w;
    const int offs = sr*DIM + 8*((g4 >> 1) ^ (sr & 7)) + 4*(g4 & 1);
    *(u32x2*)(&xh16[p][offs]) = cv.u;
  };

  // prologue: stage chunk 0 into buf 0; issue chunk-1 loads into pA
  {
    const float* xp = x + ((size_t)blockIdx.x * BM + sr) * DIM + 4*g4;
    stage_write(0, *(const f32x4*)xp);
  }
  f32x4 pA, pB;
  if (blockIdx.x + NBLK < NCHTOT) {
    const float* xp = x + ((size_t)(blockIdx.x + NBLK) * BM + sr) * DIM + 4*g4;
    pA = *(const f32x4*)xp;
  }
  asm volatile("s_waitcnt lgkmcnt(0)" ::: "memory");
  __builtin_amdgcn_s_barrier();
  asm volatile("" ::: "memory");

  // grid-stride over chunks: block b handles chunks b, b+768, b+1536, ...
  int pb = 0;
  for (int c = blockIdx.x; c < NCHTOT; c += NBLK, pb ^= 1) {
    const int R = c * BM;
    const bool havenext  = (c + NBLK     < NCHTOT);
    const bool havenext2 = (c + 2*NBLK   < NCHTOT);

    // ---- S1a: issue chunk-(k+2) loads into pB (2-deep; consumed next iter) ----
    if (havenext2) {
      const float* xp = x + ((size_t)(c + 2*NBLK) * BM + sr) * DIM + 4*g4;
      pB = *(const f32x4*)xp;
    }

    // ---- S1b: P1 on xh16[pb] -> featb[pb]. Single fp16 pass. Verbatim R20. ----
#pragma unroll
    for (int rt = 0; rt < 2; ++rt) {
      const int rr = rt*16 + li;
      const int m  = li & 7;                   // == rr&7
      f16x8 bh[2];
#pragma unroll
      for (int kb = 0; kb < 2; ++kb) {
        const int slot = 8*((4*kb + g) ^ m);
        bh[kb] = *(const f16x8*)(&xh16[pb][rr*DIM + slot]);
      }
      f32x4 acc[2];
#pragma unroll
      for (int q = 0; q < 2; ++q) acc[q] = f32x4{0.f, 0.f, 0.f, 0.f};
#pragma unroll
      for (int kb = 0; kb < 2; ++kb) {
#pragma unroll
        for (int q = 0; q < 2; ++q)
          acc[q] = __builtin_amdgcn_mfma_f32_16x16x32_f16(a1[q][kb], bh[kb], acc[q], 0, 0, 0);
      }
      // rev = proj + b_rbf; feat = cos(2*pi*rev)*SC, bf16, packed 8B write.
#pragma unroll
      for (int q = 0; q < 2; ++q) {
        float c4[4];
#pragma unroll
        for (int j = 0; j < 4; ++j) {
          float rev = acc[q][j] + brf[q][j];
          float f   = rev - floorf(rev);                 // [0,1) revolutions
          c4[j] = __builtin_amdgcn_cosf(f) * SC;
        }
        u32x2 pk;
        pk.x = cvt_pk_bf16(c4[0], c4[1]);
        pk.y = cvt_pk_bf16(c4[2], c4[3]);
        const int nt   = 2*wav + q;
        const int slot = (2*nt + (g >> 1)) ^ m;          // 16B-chunk XOR swizzle
        *(u32x2*)(&featb[pb][rr*256 + slot*8 + (g & 1)*4]) = pk;
      }
    }

    // ---- S1c: write chunk-(k+1) data (pA, issued a full iteration ago) ----
    if (havenext) stage_write(pb ^ 1, pA);

    // ---- single barrier per chunk ----
    asm volatile("s_waitcnt lgkmcnt(0)" ::: "memory");
    __builtin_amdgcn_s_barrier();
    asm volatile("" ::: "memory");

    // ---- S2: P2 on featb[pb], waves 0-3: wave = (ot, rt2). Verbatim R20. ----
    if (wav < 4) {
      const int rt2 = wav & 1;
      const int ot  = wav >> 1;
      const int rr  = rt2*16 + li;              // rows 0..31
      const int m   = li & 7;                   // == rr&7
      const int arow = (ot == 0) ? li : rowc;
      const int asw  = arow & 7;
      f32x4 acc2 = f32x4{0.f,0.f,0.f,0.f};
#pragma unroll
      for (int kb = 0; kb < 8; ++kb) {
        bf16x8 b2  = *(const bf16x8*)(&featb[pb][rr*256 + (((4*kb + g) ^ m) * 8)]);
        bf16x8 a2f = *(const bf16x8*)(&wlds[arow*NC + 8*((4*kb + g) ^ asw)]);
        acc2 = __builtin_amdgcn_mfma_f32_16x16x32_bf16(a2f, b2, acc2, 0, 0, 0);
      }
      float* op = out + (size_t)(R + rr) * OUTD;
      if (ot == 0) {
        f32x2 s0; s0.x = acc2.x + bl0.x; s0.y = acc2.y + bl0.y;
        f32x2 s1; s1.x = acc2.z + bl0.z; s1.y = acc2.w + bl0.w;
        *(f32x2*)(op + 4*g)     = s0;   // o = 4g..4g+3 (all < 16)
        *(f32x2*)(op + 4*g + 2) = s1;
      } else if (g == 0) {              // o = 16,17
        f32x2 s2; s2.x = acc2.x + bl16; s2.y = acc2.y + bl17;
        *(f32x2*)(op + 16) = s2;
      }
    }

    // ---- rotate prefetch registers (static names, no dynamic indexing) ----
    pA = pB;
  }
}

extern "C" void kernel_launch(void* const* d_in, const int* in_sizes, int n_in,
                              void* d_out, int out_size, void* d_ws, size_t ws_size,
                              hipStream_t stream) {
  (void)in_sizes; (void)n_in; (void)d_ws; (void)ws_size; (void)out_size;
  const float* x  = (const float*)d_in[0];
  const float* Wr = (const float*)d_in[1];
  const float* br = (const float*)d_in[2];
  const float* Wl = (const float*)d_in[3];
  const float* bl = (const float*)d_in[4];
  rbf_fused<<<NBLK, 512, 0, stream>>>(x, Wr, br, Wl, bl, (float*)d_out);
}

// Round 28
// 31.591 us; speedup vs baseline: 1.0192x; 1.0192x over previous
//
#include <hip/hip_runtime.h>
#include <cstdint>
#include <cstddef>

typedef __attribute__((ext_vector_type(8))) short bf16x8;
typedef __attribute__((ext_vector_type(8))) _Float16 f16x8;
typedef __attribute__((ext_vector_type(4))) float f32x4;
typedef __attribute__((ext_vector_type(2))) float f32x2;
typedef __attribute__((ext_vector_type(2))) unsigned int u32x2;

static constexpr int BROWS  = 262144;
static constexpr int DIM    = 64;
static constexpr int NC     = 256;
static constexpr int OUTD   = 18;
static constexpr int BM     = 32;              // rows per chunk
static constexpr int NCHTOT = BROWS / BM;      // 8192 chunks
static constexpr int NBLK   = 768;             // 3 blocks/CU x 256 CUs (49KB LDS each)

__device__ __forceinline__ unsigned cvt_pk_bf16(float a, float b) {
  unsigned r;
  asm("v_cvt_pk_bf16_f32 %0, %1, %2" : "=v"(r) : "v"(a), "v"(b));
  return r;
}

union U4 { unsigned u[4]; bf16x8 v; };

// pack 8 f32 -> 8 bf16 (RN), order-preserving
__device__ __forceinline__ bf16x8 pack8(const float* s) {
  U4 r;
#pragma unroll
  for (int p = 0; p < 4; ++p) r.u[p] = cvt_pk_bf16(s[2*p], s[2*p+1]);
  return r.v;
}

// Base: R20/R26 (best measured 31.37us, reproduced). Change this round:
// persistent s_setprio(1) for waves 0-3 — they execute P2(i)+P1(i+1) between
// barriers while waves 4-7 do P1(i+1) only and idle-wait, so waves 0-3 are
// always the critical path; the priority hint biases SIMD issue arbitration
// toward them (T5: helps with wave role-split, null in lockstep). Pure
// scheduling hint, zero correctness risk.
// NOTE (gfx950): __launch_bounds__(512, 8) forces 32-VGPR cap -> spill (R9).
// NOTE: prefetch->LDS pipeline is LOAD-BEARING (R24: removing it -> 100us);
// 2-deep prefetch is null-to-negative (R27).
// NOTE: epilogue-rewrite family {C-init=brf, SC-fold, v_fract, cvt_pkrtz}
// BANNED (0.15-class failures in R5/R7/R17, mechanism unknown).
__global__ __launch_bounds__(512, 4) void rbf_fused(
    const float* __restrict__ x,  const float* __restrict__ Wr,
    const float* __restrict__ br, const float* __restrict__ Wl,
    const float* __restrict__ bl, float* __restrict__ out)
{
  __shared__ __align__(16) unsigned short xh16[2][BM * DIM];    // x as fp16 bits, 2 x 4 KB
  __shared__ __align__(16) unsigned short featb[2][BM * NC];    // feat bf16 bits, 2 x 16 KB
  __shared__ __align__(16) unsigned short wlds[OUTD * NC];      // W_lin bf16 (raw), 9 KB

  const int tid  = threadIdx.x;
  const int wav  = tid >> 6;      // 0..7
  const int lane = tid & 63;
  const int li   = lane & 15;
  const int g    = lane >> 4;

  // critical-path waves (P2 + P1 per inter-barrier interval) get priority
  if (wav < 4) __builtin_amdgcn_s_setprio(1);

  const float S1 = 0.22507907903927651f;  // sqrt(2)/(2*pi): proj in revolutions
  const float SC = 0.08838834764831845f;  // sqrt(2/256), applied to feat

  // ---- stage W_lin -> LDS (bf16, swizzled) ----
  for (int idx = tid; idx < OUTD * 32; idx += 512) {
    const int r = idx >> 5, c = idx & 31;
    f32x4 v0 = *(const f32x4*)(Wl + r*NC + 8*c);
    f32x4 v1 = *(const f32x4*)(Wl + r*NC + 8*c + 4);
    float v[8];
    v[0]=v0.x; v[1]=v0.y; v[2]=v0.z; v[3]=v0.w;
    v[4]=v1.x; v[5]=v1.y; v[6]=v1.z; v[7]=v1.w;
    *(bf16x8*)(&wlds[r*NC + 8*(c ^ (r & 7))]) = pack8(v);
  }

  // ---- hoist A1 = (S1 * W_rbf)^T tile fragments, single fp16.  nt = 2*wav + q ----
  f16x8 a1[2][2];
#pragma unroll
  for (int q = 0; q < 2; ++q) {
    const int n = 16 * (2*wav + q) + li;      // component index
#pragma unroll
    for (int kb = 0; kb < 2; ++kb) {
      f16x8 f;
#pragma unroll
      for (int j = 0; j < 8; ++j)
        f[j] = (_Float16)(Wr[(size_t)(32*kb + 8*g + j) * NC + n] * S1);
      a1[q][kb] = f;
    }
  }
  f32x4 brf[2];
#pragma unroll
  for (int q = 0; q < 2; ++q)
    brf[q] = *(const f32x4*)(br + 16*(2*wav + q) + 4*g);

  const f32x4 bl0 = *(const f32x4*)(bl + 4*g);   // o = 4g..4g+3 <= 15 < 18
  const float bl16 = bl[16], bl17 = bl[17];
  const int rowc = (li < 2) ? (16 + li) : li;    // o-tile-1 A2 row (dummy rows harmless)

  const int sr = tid >> 4;   // staging row 0..31
  const int g4 = tid & 15;   // staging 4-float granule 0..15

  // stage-write: f32x4 -> fp16 (RNE), 8B write, 16B-chunk XOR swizzle
  // (chunk c16 = (g4>>1)^(sr&7)).
  auto stage_write = [&](int p, f32x4 v) {
    union { _Float16 h[4]; u32x2 u; } cv;
    cv.h[0] = (_Float16)v.x; cv.h[1] = (_Float16)v.y;
    cv.h[2] = (_Float16)v.z; cv.h[3] = (_Float16)v.w;
    const int offs = sr*DIM + 8*((g4 >> 1) ^ (sr & 7)) + 4*(g4 & 1);
    *(u32x2*)(&xh16[p][offs]) = cv.u;
  };

  // prologue: stage this block's first chunk into buf 0
  {
    const float* xp = x + ((size_t)blockIdx.x * BM + sr) * DIM + 4*g4;
    stage_write(0, *(const f32x4*)xp);
  }
  asm volatile("s_waitcnt lgkmcnt(0)" ::: "memory");
  __builtin_amdgcn_s_barrier();
  asm volatile("" ::: "memory");

  // grid-stride over chunks: block b handles chunks b, b+768, b+1536, ...
  int pb = 0;
  for (int c = blockIdx.x; c < NCHTOT; c += NBLK, pb ^= 1) {
    const int R = c * BM;

    // ---- S1a: issue next chunk's x loads early (latency hides under P1) ----
    f32x4 pnext;
    const bool havenext = (c + NBLK < NCHTOT);
    if (havenext) {
      const float* xp = x + ((size_t)(c + NBLK) * BM + sr) * DIM + 4*g4;
      pnext = *(const f32x4*)xp;
    }

    // ---- S1b: P1 on xh16[pb] -> featb[pb]. Single fp16 pass. ----
#pragma unroll
    for (int rt = 0; rt < 2; ++rt) {
      const int rr = rt*16 + li;
      const int m  = li & 7;                   // == rr&7
      f16x8 bh[2];
#pragma unroll
      for (int kb = 0; kb < 2; ++kb) {
        const int slot = 8*((4*kb + g) ^ m);
        bh[kb] = *(const f16x8*)(&xh16[pb][rr*DIM + slot]);
      }
      f32x4 acc[2];
#pragma unroll
      for (int q = 0; q < 2; ++q) acc[q] = f32x4{0.f, 0.f, 0.f, 0.f};
#pragma unroll
      for (int kb = 0; kb < 2; ++kb) {
#pragma unroll
        for (int q = 0; q < 2; ++q)
          acc[q] = __builtin_amdgcn_mfma_f32_16x16x32_f16(a1[q][kb], bh[kb], acc[q], 0, 0, 0);
      }
      // rev = proj + b_rbf; feat = cos(2*pi*rev)*SC, bf16, packed 8B write.
#pragma unroll
      for (int q = 0; q < 2; ++q) {
        float c4[4];
#pragma unroll
        for (int j = 0; j < 4; ++j) {
          float rev = acc[q][j] + brf[q][j];
          float f   = rev - floorf(rev);                 // [0,1) revolutions
          c4[j] = __builtin_amdgcn_cosf(f) * SC;
        }
        u32x2 pk;
        pk.x = cvt_pk_bf16(c4[0], c4[1]);
        pk.y = cvt_pk_bf16(c4[2], c4[3]);
        const int nt   = 2*wav + q;
        const int slot = (2*nt + (g >> 1)) ^ m;          // 16B-chunk XOR swizzle
        *(u32x2*)(&featb[pb][rr*256 + slot*8 + (g & 1)*4]) = pk;
      }
    }

    // ---- S1c: write next chunk's xh16 (other parity) ----
    if (havenext) stage_write(pb ^ 1, pnext);

    // ---- single barrier per chunk ----
    asm volatile("s_waitcnt lgkmcnt(0)" ::: "memory");
    __builtin_amdgcn_s_barrier();
    asm volatile("" ::: "memory");

    // ---- S2: P2 on featb[pb], waves 0-3: wave = (ot, rt2). ----
    if (wav < 4) {
      const int rt2 = wav & 1;
      const int ot  = wav >> 1;
      const int rr  = rt2*16 + li;              // rows 0..31
      const int m   = li & 7;                   // == rr&7
      const int arow = (ot == 0) ? li : rowc;
      const int asw  = arow & 7;
      f32x4 acc2 = f32x4{0.f,0.f,0.f,0.f};
#pragma unroll
      for (int kb = 0; kb < 8; ++kb) {
        bf16x8 b2  = *(const bf16x8*)(&featb[pb][rr*256 + (((4*kb + g) ^ m) * 8)]);
        bf16x8 a2f = *(const bf16x8*)(&wlds[arow*NC + 8*((4*kb + g) ^ asw)]);
        acc2 = __builtin_amdgcn_mfma_f32_16x16x32_bf16(a2f, b2, acc2, 0, 0, 0);
      }
      float* op = out + (size_t)(R + rr) * OUTD;
      if (ot == 0) {
        f32x2 s0; s0.x = acc2.x + bl0.x; s0.y = acc2.y + bl0.y;
        f32x2 s1; s1.x = acc2.z + bl0.z; s1.y = acc2.w + bl0.w;
        *(f32x2*)(op + 4*g)     = s0;   // o = 4g..4g+3 (all < 16)
        *(f32x2*)(op + 4*g + 2) = s1;
      } else if (g == 0) {              // o = 16,17
        f32x2 s2; s2.x = acc2.x + bl16; s2.y = acc2.y + bl17;
        *(f32x2*)(op + 16) = s2;
      }
    }
  }
}

extern "C" void kernel_launch(void* const* d_in, const int* in_sizes, int n_in,
                              void* d_out, int out_size, void* d_ws, size_t ws_size,
                              hipStream_t stream) {
  (void)in_sizes; (void)n_in; (void)d_ws; (void)ws_size; (void)out_size;
  const float* x  = (const float*)d_in[0];
  const float* Wr = (const float*)d_in[1];
  const float* br = (const float*)d_in[2];
  const float* Wl = (const float*)d_in[3];
  const float* bl = (const float*)d_in[4];
  rbf_fused<<<NBLK, 512, 0, stream>>>(x, Wr, br, Wl, bl, (float*)d_out);
}